// Round 17
// baseline (67.305 us; speedup 1.0000x reference)
//
#include <hip/hip_runtime.h>
#include <hip/hip_bf16.h>

// SimpleGATLayer fused kernel set for MI355X (gfx950).
// B=8, N=2048, F=U=128 (hard-coded from reference setup).
//
//  k_h    : W->LDS transpose + H = X@W via MFMA -> HT(b,u,n) bf16, s, t
//  k_attn : fused masked softmax(leaky(s_i+t_j)) @ H, relu, f32 out.
//           Round 17: barrier-free loop + correct VMEM queue order.
//           B-fragments direct from global (L2-resident HT) but DOUBLE-
//           BUFFERED in registers and issued one iteration ahead, pinned
//           BEFORE the A/t prefetch (sched_barrier) -> consuming B(k)
//           never drains the newest contended-L3 A group (in-order vmcnt).
//           No barriers, no loop LDS: 8 waves/CU self-skew so VALU-phase
//           and MFMA-phase waves overlap (m114). LDS only for the combine.

#define NEG_INF -1.0e9f

typedef __bf16 bf16x8 __attribute__((ext_vector_type(8)));
typedef unsigned short ushort8 __attribute__((ext_vector_type(8)));
typedef float f32x4 __attribute__((ext_vector_type(4)));

__device__ __forceinline__ unsigned short f2b(float x) {
    // f32 -> bf16 round-to-nearest-even
    unsigned u = __builtin_bit_cast(unsigned, x);
    u += 0x7fffu + ((u >> 16) & 1u);
    return (unsigned short)(u >> 16);
}

// ---------------- K1: H = X@W, plus s,t and HT (W transposed in-kernel) ----
// grid = 256 blocks x 256 thr; each wave computes 16 rows x 128 u.
__global__ __launch_bounds__(256) void k_h(const float* __restrict__ X,
                                           const float* __restrict__ W,
                                           const float* __restrict__ a,
                                           unsigned short* __restrict__ HT,
                                           float* __restrict__ sbuf,
                                           float* __restrict__ tbuf) {
    __shared__ unsigned short WT[128 * 136];   // padded stride: bank spread

    const int tid  = threadIdx.x;
    const int w    = tid >> 6;
    const int lane = tid & 63;
    const int r    = lane & 15;     // MFMA row/col index
    const int cg   = lane >> 4;     // k-group 0..3

    // cooperative W transpose: WT[u][f] = bf16(W[f][u])
    for (int i = tid; i < 16384; i += 256) {
        int u = i >> 7, f = i & 127;
        WT[u * 136 + f] = f2b(W[f * 128 + u]);
    }
    __syncthreads();

    const int row0 = blockIdx.x * 64 + w * 16;  // flattened (b*2048+n) row
    const int b    = row0 >> 11;
    const int n0   = row0 & 2047;
    const int arow = row0 + r;

    f32x4 acc[8] = {};

#pragma unroll
    for (int k0 = 0; k0 < 128; k0 += 32) {
        const float* xp = X + (size_t)arow * 128 + k0 + cg * 8;
        ushort8 xa;
#pragma unroll
        for (int j = 0; j < 8; j++) xa[j] = f2b(xp[j]);
        bf16x8 av = __builtin_bit_cast(bf16x8, xa);
#pragma unroll
        for (int ut = 0; ut < 8; ut++) {
            ushort8 wb = *(const ushort8*)(&WT[(ut * 16 + r) * 136 + k0 + cg * 8]);
            acc[ut] = __builtin_amdgcn_mfma_f32_16x16x32_bf16(
                av, __builtin_bit_cast(bf16x8, wb), acc[ut], 0, 0, 0);
        }
    }

    // D layout: lane holds H[row0 + cg*4 + reg][ut*16 + r]
    float sp[4] = {0.f, 0.f, 0.f, 0.f};
    float tp[4] = {0.f, 0.f, 0.f, 0.f};
#pragma unroll
    for (int ut = 0; ut < 8; ut++) {
        int u = ut * 16 + r;
        float as = a[u];
        float ad = a[128 + u];
#pragma unroll
        for (int reg = 0; reg < 4; reg++) {
            float h = acc[ut][reg];
            int nrow = n0 + cg * 4 + reg;
            HT[((size_t)b * 128 + u) * 2048 + nrow] = f2b(h);
            sp[reg] += h * as;
            tp[reg] += h * ad;
        }
    }
#pragma unroll
    for (int msk = 1; msk < 16; msk <<= 1) {
#pragma unroll
        for (int reg = 0; reg < 4; reg++) {
            sp[reg] += __shfl_xor(sp[reg], msk);
            tp[reg] += __shfl_xor(tp[reg], msk);
        }
    }
    if (r == 0) {
#pragma unroll
        for (int reg = 0; reg < 4; reg++) {
            int row = row0 + cg * 4 + reg;
            sbuf[row] = sp[reg];
            tbuf[row] = tp[reg];
        }
    }
}

// ---------------- K2: fused masked-softmax attention @ H ----------------
// grid = 512 blocks (2/CU), block = 256 thr (4 waves, one per j-quarter).
// Block: 32 i-rows x 128 u of batch b = bid&7. Wave jq owns all 32 rows
// (two A-fragments: rows r, r+16) x its 512-j quarter (16 tiles of 32).
// Loop: NO barriers, NO LDS. Register pipeline per iteration k:
//   [issue B(k+1): 8x ushort8 direct-global]  <- pinned oldest
//   [issue A/t(k+2): depth-2 copy-then-refill]
//   [P(k) VALU from A/t(k) regs]  [MFMA with B(k) regs (issued iter k-1)]
// Consuming B(k) leaves [A/t(k+1), B(k+1), A/t(k+2)] in flight (compiler
// vmcnt) -> B flight = 1 iter, A flight = 2 iters, no cross-drain.
__global__ __launch_bounds__(256) void k_attn(const int* __restrict__ A,
                                              const unsigned short* __restrict__ HT,
                                              const float* __restrict__ sbuf,
                                              const float* __restrict__ tbuf,
                                              float* __restrict__ out) {
    __shared__ float accS[3 * 32 * 132];   // 50.7 KB (combine only)
    __shared__ float dSm[4][32];

    const int tid  = threadIdx.x;
    const int jq   = tid >> 6;          // 0..3 j-quarter (512 j)
    const int lane = tid & 63;
    const int r    = lane & 15;
    const int cg   = lane >> 4;
    const int bid  = blockIdx.x;
    const int b    = bid & 7;           // batch pinned per XCD
    const int it   = bid >> 3;          // 0..63 i-tile
    const int i0   = it * 32;
    const int rot  = it & 15;           // per-block j-tile rotation

    const int irow0 = i0 + r;           // row group 0; group 1 = +16
    const float s0 = sbuf[b * 2048 + irow0];
    const float s1 = sbuf[b * 2048 + irow0 + 16];
    const unsigned short* Hb = HT + ((size_t)b * 128) * 2048 + jq * 512;
    const unsigned short* Hrow = Hb + (size_t)r * 2048;   // + ut*16*2048 + jb
    const int*   Aq0 = A    + ((size_t)(b * 2048 + irow0)) * 2048 + jq * 512 + cg * 8;
    const int*   Aq1 = Aq0 + 16 * 2048;
    const float* Tq  = tbuf + (size_t)b * 2048 + jq * 512 + cg * 8;

    f32x4 acc0[8] = {};
    f32x4 acc1[8] = {};
    float den0 = 0.f, den1 = 0.f;

    // ---- register pipeline state ----
    ushort8 bP[2][8];              // B double buffer (slot k&1)
    int4   aP0[2][2], aP1[2][2];   // A depth-2 (copy-then-refill)
    float4 tP[2][2];

    // ---- prologue: B(0); A/t(0),(1) ----
    {
        const int j0 = rot * 32;
        const int j1 = ((1 + rot) & 15) * 32;
#pragma unroll
        for (int ut = 0; ut < 8; ut++)
            bP[0][ut] = *(const ushort8*)(Hrow + (size_t)(ut * 16) * 2048 +
                                          j0 + cg * 8);
        aP0[0][0] = *(const int4*)(Aq0 + j0);
        aP0[0][1] = *(const int4*)(Aq0 + j0 + 4);
        aP1[0][0] = *(const int4*)(Aq1 + j0);
        aP1[0][1] = *(const int4*)(Aq1 + j0 + 4);
        tP[0][0]  = *(const float4*)(Tq + j0);
        tP[0][1]  = *(const float4*)(Tq + j0 + 4);
        aP0[1][0] = *(const int4*)(Aq0 + j1);
        aP0[1][1] = *(const int4*)(Aq0 + j1 + 4);
        aP1[1][0] = *(const int4*)(Aq1 + j1);
        aP1[1][1] = *(const int4*)(Aq1 + j1 + 4);
        tP[1][0]  = *(const float4*)(Tq + j1);
        tP[1][1]  = *(const float4*)(Tq + j1 + 4);
    }

#pragma unroll
    for (int k = 0; k < 16; ++k) {
        const int p = k & 1;

        // consume A/t slot (register copies) so it can be refilled
        int4   ca0 = aP0[p][0], ca1 = aP0[p][1];
        int4   cb0 = aP1[p][0], cb1 = aP1[p][1];
        float4 ct0 = tP[p][0],  ct1 = tP[p][1];

        // ---- issue B(k+1) FIRST (oldest in this iteration's queue) ----
        if (k < 15) {
            const int jn = ((k + 1 + rot) & 15) * 32 + cg * 8;
#pragma unroll
            for (int ut = 0; ut < 8; ut++)
                bP[p ^ 1][ut] = *(const ushort8*)(Hrow +
                                    (size_t)(ut * 16) * 2048 + jn);
        }
        __builtin_amdgcn_sched_barrier(0);   // pin: B(k+1) before A/t(k+2)
        // ---- issue A/t(k+2) into slot p ----
        if (k < 14) {
            const int ja = ((k + 2 + rot) & 15) * 32;
            aP0[p][0] = *(const int4*)(Aq0 + ja);
            aP0[p][1] = *(const int4*)(Aq0 + ja + 4);
            aP1[p][0] = *(const int4*)(Aq1 + ja);
            aP1[p][1] = *(const int4*)(Aq1 + ja + 4);
            tP[p][0]  = *(const float4*)(Tq + ja);
            tP[p][1]  = *(const float4*)(Tq + ja + 4);
        }
        __builtin_amdgcn_sched_barrier(0);   // pin: loads issued before VALU

        // ---- P fragments for both row groups (t shared) ----
        float tv[8] = {ct0.x, ct0.y, ct0.z, ct0.w, ct1.x, ct1.y, ct1.z, ct1.w};
        int   a0i[8] = {ca0.x, ca0.y, ca0.z, ca0.w, ca1.x, ca1.y, ca1.z, ca1.w};
        int   a1i[8] = {cb0.x, cb0.y, cb0.z, cb0.w, cb1.x, cb1.y, cb1.z, cb1.w};
        bf16x8 pa0, pa1;
#pragma unroll
        for (int jj = 0; jj < 8; jj++) {
            float x0 = s0 + tv[jj];
            float e0 = fmaxf(x0, 0.2f * x0);
            float p0 = __expf(e0 - 16.0f);
            p0 = a0i[jj] > 0 ? p0 : 0.f;
            den0 += p0;
            pa0[jj] = (__bf16)p0;

            float x1 = s1 + tv[jj];
            float e1 = fmaxf(x1, 0.2f * x1);
            float p1 = __expf(e1 - 16.0f);
            p1 = a1i[jj] > 0 ? p1 : 0.f;
            den1 += p1;
            pa1[jj] = (__bf16)p1;
        }

        // ---- 16 MFMA from B(k) regs (loaded one iteration ago) ----
#pragma unroll
        for (int ut = 0; ut < 8; ut++) {
            bf16x8 hb = __builtin_bit_cast(bf16x8, bP[p][ut]);
            acc0[ut] = __builtin_amdgcn_mfma_f32_16x16x32_bf16(pa0, hb, acc0[ut], 0, 0, 0);
            acc1[ut] = __builtin_amdgcn_mfma_f32_16x16x32_bf16(pa1, hb, acc1[ut], 0, 0, 0);
        }
    }

    // per-wave denominators per row (sum over the 4 cg k-groups)
    den0 += __shfl_xor(den0, 16);
    den0 += __shfl_xor(den0, 32);
    den1 += __shfl_xor(den1, 16);
    den1 += __shfl_xor(den1, 32);

    if (cg == 0) { dSm[jq][r] = den0; dSm[jq][16 + r] = den1; }
    if (jq != 0) {
        const int base = (jq - 1) * 32;
#pragma unroll
        for (int ut = 0; ut < 8; ut++)
#pragma unroll
            for (int reg = 0; reg < 4; reg++) {
                accS[(base + cg * 4 + reg) * 132 + ut * 16 + r]      = acc0[ut][reg];
                accS[(base + 16 + cg * 4 + reg) * 132 + ut * 16 + r] = acc1[ut][reg];
            }
    }
    __syncthreads();
    if (jq == 0) {
        float dinv0[4], dinv1[4];
#pragma unroll
        for (int reg = 0; reg < 4; reg++) {
            const int row0_ = cg * 4 + reg;
            const int row1_ = 16 + cg * 4 + reg;
            dinv0[reg] = 1.0f / (dSm[0][row0_] + dSm[1][row0_] +
                                 dSm[2][row0_] + dSm[3][row0_]);
            dinv1[reg] = 1.0f / (dSm[0][row1_] + dSm[1][row1_] +
                                 dSm[2][row1_] + dSm[3][row1_]);
        }
#pragma unroll
        for (int ut = 0; ut < 8; ut++) {
#pragma unroll
            for (int reg = 0; reg < 4; reg++) {
                const int lr0 = cg * 4 + reg;
                const int lr1 = 16 + cg * 4 + reg;
                float n0 = acc0[ut][reg]
                         + accS[(0 * 32 + lr0) * 132 + ut * 16 + r]
                         + accS[(1 * 32 + lr0) * 132 + ut * 16 + r]
                         + accS[(2 * 32 + lr0) * 132 + ut * 16 + r];
                float n1 = acc1[ut][reg]
                         + accS[(0 * 32 + lr1) * 132 + ut * 16 + r]
                         + accS[(1 * 32 + lr1) * 132 + ut * 16 + r]
                         + accS[(2 * 32 + lr1) * 132 + ut * 16 + r];
                out[((size_t)(b * 2048 + i0 + lr0)) * 128 + ut * 16 + r] =
                    fmaxf(n0 * dinv0[reg], 0.f);
                out[((size_t)(b * 2048 + i0 + lr1)) * 128 + ut * 16 + r] =
                    fmaxf(n1 * dinv1[reg], 0.f);
            }
        }
    }
}

extern "C" void kernel_launch(void* const* d_in, const int* in_sizes, int n_in,
                              void* d_out, int out_size, void* d_ws, size_t ws_size,
                              hipStream_t stream) {
    const float* X = (const float*)d_in[0];   // (8,2048,128) f32
    const int*   A = (const int*)d_in[1];     // (8,2048,2048) i32
    const float* W = (const float*)d_in[2];   // (128,128) f32
    const float* a = (const float*)d_in[3];   // (256,1) f32
    float* out = (float*)d_out;               // (8,2048,128) f32

    char* ws = (char*)d_ws;
    float*          sb  = (float*)(ws);                           // 64 KB
    float*          tb  = (float*)(ws + 65536);                   // 64 KB
    unsigned short* HT  = (unsigned short*)(ws + 131072);         // 4 MB

    k_h<<<dim3(256), dim3(256), 0, stream>>>(X, W, a, HT, sb, tb);
    k_attn<<<dim3(512), dim3(256), 0, stream>>>(A, HT, sb, tb, out);
}